// Round 9
// baseline (4060.279 us; speedup 1.0000x reference)
//
#include <hip/hip_runtime.h>
#include <hip/hip_cooperative_groups.h>

namespace cg = cooperative_groups;

// ConvexPolytopeManifold: dual-PGD QP projection. B=4096, n=512, m=1024.
// Round 9:
//  - pgd_phase gets __launch_bounds__(256,2): caps VGPR at 256/wave so 2
//    blocks/CU co-reside -> 512-block cooperative launch validates (round-8
//    failure: no min-waves bound -> >256 VGPR -> 1 block/CU -> coop launch
//    rejected silently; out degenerated to ~u, absmax 0.67)
//  - cooperative launch return code CHECKED; on failure fall back to the
//    round-6 per-iteration dispatch loop (deterministic branch, capture-safe)
//
// math:
//   Q = A@A^T; y = x+u; c = y@A^T - b
//   lam1 = step*relu(c); 49x lam = relu(lam - 0.01*(lam@Q - c))
//   active = (c - lam@Q >= -TOL)
//   masked = (u@A^T) * active; lam1 = step*relu(masked)
//   9x lam = relu(lam - 0.01*(lam@Q - masked)) * active
//   out = u - lam@A

#define TOLV 1e-5f
#define STEPV 0.01f

typedef __attribute__((ext_vector_type(8))) short short8;
typedef __attribute__((ext_vector_type(4))) float floatx4;
typedef unsigned short ushort_t;

#define GLDS(gptr, lptr) \
    __builtin_amdgcn_global_load_lds( \
        (const __attribute__((address_space(1))) void*)(gptr), \
        (__attribute__((address_space(3))) void*)(lptr), 16, 0, 0)

__device__ inline ushort_t f2bf(float f) {
    union { float f; unsigned int u; } c; c.f = f;
    unsigned int u = c.u;
    return (ushort_t)((u + 0x7FFFu + ((u >> 16) & 1u)) >> 16);   // RNE
}
__device__ inline float bf2f(ushort_t h) {
    union { unsigned int u; float f; } c; c.u = ((unsigned int)h) << 16;
    return c.f;
}

__global__ void addcast_kernel(const float* __restrict__ x, const float* __restrict__ u,
                               ushort_t* __restrict__ ybf, ushort_t* __restrict__ ubf, int n) {
    int idx = (blockIdx.x * blockDim.x + threadIdx.x) * 4;
    if (idx < n) {
        float4 xv = *(const float4*)(x + idx);
        float4 uv = *(const float4*)(u + idx);
        ushort4 yo, uo;
        yo.x = f2bf(xv.x + uv.x); yo.y = f2bf(xv.y + uv.y);
        yo.z = f2bf(xv.z + uv.z); yo.w = f2bf(xv.w + uv.w);
        uo.x = f2bf(uv.x); uo.y = f2bf(uv.y); uo.z = f2bf(uv.z); uo.w = f2bf(uv.w);
        *(ushort4*)(ybf + idx) = yo;
        *(ushort4*)(ubf + idx) = uo;
    }
}

__global__ void cvt_bf16_kernel(const float* __restrict__ src, ushort_t* __restrict__ dst, int n) {
    int idx = (blockIdx.x * blockDim.x + threadIdx.x) * 4;
    if (idx < n) {
        float4 v = *(const float4*)(src + idx);
        ushort4 o;
        o.x = f2bf(v.x); o.y = f2bf(v.y); o.z = f2bf(v.z); o.w = f2bf(v.w);
        *(ushort4*)(dst + idx) = o;
    }
}

__global__ void transpose_cast_kernel(const float* __restrict__ A, ushort_t* __restrict__ AT,
                                      int m, int n) {
    __shared__ float t[32][33];
    int bx = blockIdx.x * 32;
    int by = blockIdx.y * 32;
    int tx = threadIdx.x & 31, ty = threadIdx.x >> 5;   // 32 x 8
#pragma unroll
    for (int i = 0; i < 32; i += 8)
        t[ty + i][tx] = A[(size_t)(by + ty + i) * n + bx + tx];
    __syncthreads();
#pragma unroll
    for (int i = 0; i < 32; i += 8)
        AT[(size_t)(bx + ty + i) * m + by + tx] = f2bf(t[tx][ty + i]);
}

// ---------------- one-shot bf16 MFMA GEMM:  C = X @ W^T ----------------
// Tile 64Mx128N, 256 thr = 4 waves, wave tile 32x64, BK=64, XOR-swizzled LDS,
// XCD-aware 1D grid (nbm % 8 == 0 for all shapes used).
// EPI: 0 Q:      lamHout = bf16(v)
//      1 c+lam1: cv=v-bvec[col]; cFout=cv; cHout=bf16(cv);
//                l=step*relu(cv); lamFout=l; lamHout=bf16(l)
//      2 iter:   nv=relu(lamFin - step*(v - bf2f(cH))); lamFout; lamHout  [fallback]
//      3 iter*act                                                         [fallback]
//      4 act:    actOut = (cF - v >= -TOL) ? 1 : 0  (bf16)
//      5 masked+lam1: mv=v*act; cHout=bf16(mv); l=step*relu(mv); lamFout; lamHout
//      6 final:  outF = lamFin(=u) - v
template<int EPI>
__global__ __launch_bounds__(256)
void mfma_g(const ushort_t* __restrict__ X, const ushort_t* __restrict__ W,
            const float* __restrict__ lamFin, const float* __restrict__ cF,
            const ushort_t* __restrict__ cH, const ushort_t* __restrict__ actb,
            float* __restrict__ lamFout, ushort_t* __restrict__ lamHout,
            float* __restrict__ cFout, ushort_t* __restrict__ cHout,
            ushort_t* __restrict__ actOut, float* __restrict__ outF,
            const float* __restrict__ bvec,
            int M, int N, int K) {
    __shared__ short As[64 * 64];    //  8 KB
    __shared__ short Bs[128 * 64];   // 16 KB

    const int tid = threadIdx.x;
    const int w = tid >> 6;
    const int lane = tid & 63;

    const int nbm = M >> 6;
    const int spx = nbm >> 3;
    const int xcd = blockIdx.x & 7;
    const int loc = blockIdx.x >> 3;
    const int bm = (xcd * spx + (loc % spx)) << 6;
    const int bn = (loc / spx) << 7;

    const int wm = (w & 1) * 32;
    const int wn = (w >> 1) * 64;
    const int quad = lane >> 4;
    const int l15 = lane & 15;

    const int ldr = lane >> 3;
    const int csw = ((lane & 7) ^ ldr) * 8;

    floatx4 acc[2][4] = {};

    for (int k0 = 0; k0 < K; k0 += 64) {
#pragma unroll
        for (int t = 0; t < 2; ++t) {
            const ushort_t* ga = X + (size_t)(bm + w * 16 + t * 8 + ldr) * K + k0 + csw;
            GLDS(ga, As + (w * 16 + t * 8) * 64);
        }
#pragma unroll
        for (int t = 0; t < 4; ++t) {
            const ushort_t* gb = W + (size_t)(bn + w * 32 + t * 8 + ldr) * K + k0 + csw;
            GLDS(gb, Bs + (w * 32 + t * 8) * 64);
        }
        __syncthreads();
#pragma unroll
        for (int kk = 0; kk < 2; ++kk) {
            const int sw = ((kk * 4 + quad) ^ (l15 & 7)) * 8;
            short8 af[2], bfr[4];
#pragma unroll
            for (int i = 0; i < 2; ++i)
                af[i] = *(const short8*)(As + (wm + i * 16 + l15) * 64 + sw);
#pragma unroll
            for (int i = 0; i < 4; ++i)
                bfr[i] = *(const short8*)(Bs + (wn + i * 16 + l15) * 64 + sw);
#pragma unroll
            for (int mt = 0; mt < 2; ++mt)
#pragma unroll
                for (int nt = 0; nt < 4; ++nt)
                    acc[mt][nt] = __builtin_amdgcn_mfma_f32_16x16x32_bf16(
                        af[mt], bfr[nt], acc[mt][nt], 0, 0, 0);
        }
        __syncthreads();
    }

#pragma unroll
    for (int mt = 0; mt < 2; ++mt) {
#pragma unroll
        for (int nt = 0; nt < 4; ++nt) {
#pragma unroll
            for (int r = 0; r < 4; ++r) {
                int row = bm + wm + mt * 16 + quad * 4 + r;
                int col = bn + wn + nt * 16 + l15;
                size_t idx = (size_t)row * N + col;
                float v = acc[mt][nt][r];
                if (EPI == 0) {
                    lamHout[idx] = f2bf(v);
                } else if (EPI == 1) {
                    float cv = v - bvec[col];
                    cFout[idx] = cv;
                    cHout[idx] = f2bf(cv);
                    float l = STEPV * fmaxf(cv, 0.0f);
                    lamFout[idx] = l;
                    lamHout[idx] = f2bf(l);
                } else if (EPI == 2) {
                    float nv = fmaxf(fmaf(-STEPV, v - bf2f(cH[idx]), lamFin[idx]), 0.0f);
                    lamFout[idx] = nv;
                    lamHout[idx] = f2bf(nv);
                } else if (EPI == 3) {
                    float nv = fmaxf(fmaf(-STEPV, v - bf2f(cH[idx]), lamFin[idx]), 0.0f)
                               * bf2f(actb[idx]);
                    lamFout[idx] = nv;
                    lamHout[idx] = f2bf(nv);
                } else if (EPI == 4) {
                    actOut[idx] = (cF[idx] - v >= -TOLV) ? (ushort_t)0x3F80 : (ushort_t)0;
                } else if (EPI == 5) {
                    float mv = v * bf2f(actb[idx]);
                    cHout[idx] = f2bf(mv);
                    float l = STEPV * fmaxf(mv, 0.0f);
                    lamFout[idx] = l;
                    lamHout[idx] = f2bf(l);
                } else if (EPI == 6) {
                    outF[idx] = lamFin[idx] - v;
                }
            }
        }
    }
}

// ---------------- persistent cooperative PGD phase ----------------
// lam/c/act state in registers; bf16 lam ping-pongs bufA/bufB; grid 512
// (= 2 blocks/CU guaranteed by __launch_bounds__(256,2)); final in bufB
// (iters odd: 49, 9).
template<int MASK>
__global__ __launch_bounds__(256, 2)
void pgd_phase(const ushort_t* __restrict__ Qw, const ushort_t* __restrict__ cH,
               const ushort_t* __restrict__ actH,
               ushort_t* __restrict__ bufA, ushort_t* __restrict__ bufB,
               int iters) {
    constexpr int N = 1024, K = 1024;
    __shared__ short As[64 * 64];
    __shared__ short Bs[128 * 64];

    const int tid = threadIdx.x;
    const int w = tid >> 6;
    const int lane = tid & 63;

    const int spx = 8;                       // (4096/64)/8
    const int xcd = blockIdx.x & 7;
    const int loc = blockIdx.x >> 3;
    const int bm = (xcd * spx + (loc % spx)) << 6;
    const int bn = (loc / spx) << 7;

    const int wm = (w & 1) * 32;
    const int wn = (w >> 1) * 64;
    const int quad = lane >> 4;
    const int l15 = lane & 15;

    const int ldr = lane >> 3;
    const int csw = ((lane & 7) ^ ldr) * 8;

    float c_reg[32], lamf[32], areg[MASK ? 32 : 1];
    int idxs[32];
#pragma unroll
    for (int mt = 0; mt < 2; ++mt)
#pragma unroll
        for (int nt = 0; nt < 4; ++nt)
#pragma unroll
            for (int r = 0; r < 4; ++r) {
                int i = mt * 16 + nt * 4 + r;
                int row = bm + wm + mt * 16 + quad * 4 + r;
                int col = bn + wn + nt * 16 + l15;
                int idx = row * N + col;
                idxs[i] = idx;
                float cv = bf2f(cH[idx]);
                c_reg[i] = cv;
                lamf[i] = STEPV * fmaxf(cv, 0.0f);   // lam1
                if (MASK) areg[i] = bf2f(actH[idx]);
            }

    cg::grid_group grid = cg::this_grid();

    for (int it = 0; it < iters; ++it) {
        const ushort_t* cur = (it & 1) ? bufB : bufA;
        ushort_t* nxt = (it & 1) ? bufA : bufB;

        floatx4 acc[2][4] = {};
        for (int k0 = 0; k0 < K; k0 += 64) {
#pragma unroll
            for (int t = 0; t < 2; ++t) {
                const ushort_t* ga = cur + (size_t)(bm + w * 16 + t * 8 + ldr) * K + k0 + csw;
                GLDS(ga, As + (w * 16 + t * 8) * 64);
            }
#pragma unroll
            for (int t = 0; t < 4; ++t) {
                const ushort_t* gb = Qw + (size_t)(bn + w * 32 + t * 8 + ldr) * K + k0 + csw;
                GLDS(gb, Bs + (w * 32 + t * 8) * 64);
            }
            __syncthreads();
#pragma unroll
            for (int kk = 0; kk < 2; ++kk) {
                const int sw = ((kk * 4 + quad) ^ (l15 & 7)) * 8;
                short8 af[2], bfr[4];
#pragma unroll
                for (int i = 0; i < 2; ++i)
                    af[i] = *(const short8*)(As + (wm + i * 16 + l15) * 64 + sw);
#pragma unroll
                for (int i = 0; i < 4; ++i)
                    bfr[i] = *(const short8*)(Bs + (wn + i * 16 + l15) * 64 + sw);
#pragma unroll
                for (int mt = 0; mt < 2; ++mt)
#pragma unroll
                    for (int nt = 0; nt < 4; ++nt)
                        acc[mt][nt] = __builtin_amdgcn_mfma_f32_16x16x32_bf16(
                            af[mt], bfr[nt], acc[mt][nt], 0, 0, 0);
            }
            __syncthreads();
        }

#pragma unroll
        for (int mt = 0; mt < 2; ++mt)
#pragma unroll
            for (int nt = 0; nt < 4; ++nt)
#pragma unroll
                for (int r = 0; r < 4; ++r) {
                    int i = mt * 16 + nt * 4 + r;
                    float v = acc[mt][nt][r];
                    float nv = fmaxf(fmaf(-STEPV, v - c_reg[i], lamf[i]), 0.0f);
                    if (MASK) nv *= areg[i];
                    lamf[i] = nv;
                    nxt[idxs[i]] = f2bf(nv);
                }

        grid.sync();
    }
}

static inline int grid1d(int M, int N) { return (M >> 6) * (N >> 7); }

extern "C" void kernel_launch(void* const* d_in, const int* in_sizes, int n_in,
                              void* d_out, int out_size, void* d_ws, size_t ws_size,
                              hipStream_t stream) {
    const float* x = (const float*)d_in[0];  // [B,n]
    const float* u = (const float*)d_in[1];  // [B,n]
    const float* A = (const float*)d_in[2];  // [m,n]
    const float* b = (const float*)d_in[3];  // [m]
    float* out = (float*)d_out;              // [B,n]

    const int B = 4096, n = 512, m = 1024;
    const size_t Bm = (size_t)B * m;
    const size_t Bn = (size_t)B * n;

    ushort_t* A_bf   = (ushort_t*)d_ws;            // [m,n]
    ushort_t* AT_bf  = A_bf + (size_t)m * n;       // [n,m]
    ushort_t* y_bf   = AT_bf + (size_t)n * m;      // [B,n]
    ushort_t* u_bf   = y_bf + Bn;                  // [B,n]
    ushort_t* Qbf    = u_bf + Bn;                  // [m,m]
    ushort_t* lamH_A = Qbf + (size_t)m * m;        // [B,m]
    ushort_t* lamH_B = lamH_A + Bm;                // [B,m]
    ushort_t* act    = lamH_B + Bm;                // [B,m] bf16 0/1
    ushort_t* cHbuf  = act + Bm;                   // [B,m] bf16 (c, then masked)
    float* cFbuf  = (float*)(cHbuf + Bm);          // [B,m] f32 (c, for act test)
    float* lamF_A = cFbuf + Bm;                    // [B,m] f32 (fallback only)
    float* lamF_B = lamF_A + Bm;                   // [B,m] f32 (fallback only)

    dim3 blk(256);

    addcast_kernel<<<(int)(Bn / 4 + 255) / 256, 256, 0, stream>>>(x, u, y_bf, u_bf, (int)Bn);
    cvt_bf16_kernel<<<(m * n / 4 + 255) / 256, 256, 0, stream>>>(A, A_bf, m * n);
    transpose_cast_kernel<<<dim3(n / 32, m / 32), dim3(256), 0, stream>>>(A, AT_bf, m, n);

    // Q = bf16(A @ A^T)
    mfma_g<0><<<grid1d(m, m), blk, 0, stream>>>(
        A_bf, A_bf, nullptr, nullptr, nullptr, nullptr,
        nullptr, Qbf, nullptr, nullptr, nullptr, nullptr, nullptr, m, m, n);

    // c = y@A^T - b; lam1 = step*relu(c) (fp32 + bf16)
    mfma_g<1><<<grid1d(B, m), blk, 0, stream>>>(
        y_bf, A_bf, nullptr, nullptr, nullptr, nullptr,
        lamF_A, lamH_A, cFbuf, cHbuf, nullptr, nullptr, b, B, m, n);

    // phase 1: 49 iterations -> lam50 bf16 in lamH_B
    int it1 = 49, it2 = 9;
    {
        void* args[] = {(void*)&Qbf, (void*)&cHbuf, (void*)&act,
                        (void*)&lamH_A, (void*)&lamH_B, (void*)&it1};
        hipError_t e = hipLaunchCooperativeKernel((void*)pgd_phase<0>, dim3(512), blk,
                                                  args, 0, stream);
        if (e != hipSuccess) {
            float* lfin = lamF_A; float* lfout = lamF_B;
            ushort_t* lhin = lamH_A; ushort_t* lhout = lamH_B;
            for (int it = 0; it < 49; ++it) {
                mfma_g<2><<<grid1d(B, m), blk, 0, stream>>>(
                    lhin, Qbf, lfin, nullptr, cHbuf, nullptr,
                    lfout, lhout, nullptr, nullptr, nullptr, nullptr, nullptr, B, m, m);
                float* tf = lfin; lfin = lfout; lfout = tf;
                ushort_t* th = lhin; lhin = lhout; lhout = th;
            }
        }
    }

    // active = (c - lam50@Q >= -TOL)
    mfma_g<4><<<grid1d(B, m), blk, 0, stream>>>(
        lamH_B, Qbf, nullptr, cFbuf, nullptr, nullptr,
        nullptr, nullptr, nullptr, nullptr, act, nullptr, nullptr, B, m, m);

    // masked = (u@A^T)*active -> cHbuf; lam1 = step*relu(masked)
    mfma_g<5><<<grid1d(B, m), blk, 0, stream>>>(
        u_bf, A_bf, nullptr, nullptr, nullptr, act,
        lamF_A, lamH_A, nullptr, cHbuf, nullptr, nullptr, nullptr, B, m, n);

    // phase 2: 9 iterations -> lam10 bf16 in lamH_B
    {
        void* args[] = {(void*)&Qbf, (void*)&cHbuf, (void*)&act,
                        (void*)&lamH_A, (void*)&lamH_B, (void*)&it2};
        hipError_t e = hipLaunchCooperativeKernel((void*)pgd_phase<1>, dim3(512), blk,
                                                  args, 0, stream);
        if (e != hipSuccess) {
            float* lfin = lamF_A; float* lfout = lamF_B;
            ushort_t* lhin = lamH_A; ushort_t* lhout = lamH_B;
            for (int it = 0; it < 9; ++it) {
                mfma_g<3><<<grid1d(B, m), blk, 0, stream>>>(
                    lhin, Qbf, lfin, nullptr, cHbuf, act,
                    lfout, lhout, nullptr, nullptr, nullptr, nullptr, nullptr, B, m, m);
                float* tf = lfin; lfin = lfout; lfout = tf;
                ushort_t* th = lhin; lhin = lhout; lhout = th;
            }
        }
    }

    // out = u - lam @ A
    mfma_g<6><<<grid1d(B, n), blk, 0, stream>>>(
        lamH_B, AT_bf, u, nullptr, nullptr, nullptr,
        nullptr, nullptr, nullptr, nullptr, nullptr, out, nullptr, B, n, m);
}

// Round 10
// 1377.342 us; speedup vs baseline: 2.9479x; 2.9479x over previous
//
#include <hip/hip_runtime.h>

// ConvexPolytopeManifold: dual-PGD QP projection. B=4096, n=512, m=1024.
// Round 10:
//  - ABANDON cooperative persistent kernel (r9: grid.sync flushes L2 every
//    iteration -> 402 MB HBM writes/dispatch, 70 us/iter vs 23 for dispatch loop)
//  - back to r6 dispatch-loop structure, now with DOUBLE-BUFFERED LDS staging:
//    prefetch for K-iter kt+1 issued after the barrier of kt, drained at the
//    barrier of kt+1 -> global->LDS latency overlaps MFMA; 1 barrier/K-iter.
//  - iterations read c as bf16 (step-damped); fp32 c kept for the active test;
//    fp32 lam master + bf16 shadow (unchanged numerics from r9 fallback).
//
// math:
//   Q = A@A^T; y = x+u; c = y@A^T - b
//   lam1 = step*relu(c); 49x lam = relu(lam - 0.01*(lam@Q - c))
//   active = (c - lam@Q >= -TOL)
//   masked = (u@A^T) * active; lam1 = step*relu(masked)
//   9x lam = relu(lam - 0.01*(lam@Q - masked)) * active
//   out = u - lam@A

#define TOLV 1e-5f
#define STEPV 0.01f

typedef __attribute__((ext_vector_type(8))) short short8;
typedef __attribute__((ext_vector_type(4))) float floatx4;
typedef unsigned short ushort_t;

#define GLDS(gptr, lptr) \
    __builtin_amdgcn_global_load_lds( \
        (const __attribute__((address_space(1))) void*)(gptr), \
        (__attribute__((address_space(3))) void*)(lptr), 16, 0, 0)

__device__ inline ushort_t f2bf(float f) {
    union { float f; unsigned int u; } c; c.f = f;
    unsigned int u = c.u;
    return (ushort_t)((u + 0x7FFFu + ((u >> 16) & 1u)) >> 16);   // RNE
}
__device__ inline float bf2f(ushort_t h) {
    union { unsigned int u; float f; } c; c.u = ((unsigned int)h) << 16;
    return c.f;
}

__global__ void addcast_kernel(const float* __restrict__ x, const float* __restrict__ u,
                               ushort_t* __restrict__ ybf, ushort_t* __restrict__ ubf, int n) {
    int idx = (blockIdx.x * blockDim.x + threadIdx.x) * 4;
    if (idx < n) {
        float4 xv = *(const float4*)(x + idx);
        float4 uv = *(const float4*)(u + idx);
        ushort4 yo, uo;
        yo.x = f2bf(xv.x + uv.x); yo.y = f2bf(xv.y + uv.y);
        yo.z = f2bf(xv.z + uv.z); yo.w = f2bf(xv.w + uv.w);
        uo.x = f2bf(uv.x); uo.y = f2bf(uv.y); uo.z = f2bf(uv.z); uo.w = f2bf(uv.w);
        *(ushort4*)(ybf + idx) = yo;
        *(ushort4*)(ubf + idx) = uo;
    }
}

__global__ void cvt_bf16_kernel(const float* __restrict__ src, ushort_t* __restrict__ dst, int n) {
    int idx = (blockIdx.x * blockDim.x + threadIdx.x) * 4;
    if (idx < n) {
        float4 v = *(const float4*)(src + idx);
        ushort4 o;
        o.x = f2bf(v.x); o.y = f2bf(v.y); o.z = f2bf(v.z); o.w = f2bf(v.w);
        *(ushort4*)(dst + idx) = o;
    }
}

__global__ void transpose_cast_kernel(const float* __restrict__ A, ushort_t* __restrict__ AT,
                                      int m, int n) {
    __shared__ float t[32][33];
    int bx = blockIdx.x * 32;
    int by = blockIdx.y * 32;
    int tx = threadIdx.x & 31, ty = threadIdx.x >> 5;   // 32 x 8
#pragma unroll
    for (int i = 0; i < 32; i += 8)
        t[ty + i][tx] = A[(size_t)(by + ty + i) * n + bx + tx];
    __syncthreads();
#pragma unroll
    for (int i = 0; i < 32; i += 8)
        AT[(size_t)(bx + ty + i) * m + by + tx] = f2bf(t[tx][ty + i]);
}

// ---------------- bf16 MFMA GEMM, double-buffered:  C = X @ W^T ----------------
// X=[M,K] bf16, W=[N,K] bf16. 256 thr = 4 waves. Tile 64Mx128N, BK=64,
// wave tile 32x64 (2x4 of 16x16x32). XOR-swizzled LDS; XCD-aware 1D grid.
// K-loop: prologue-stage buf0; each iter: barrier -> prefetch other buf
// (async, drains at NEXT barrier) -> ds_read+MFMA current buf.
// EPI: 0 Q:      lamHout = bf16(v)
//      1 c+lam1: cv=v-bvec[col]; cFout=cv; cHout=bf16(cv);
//                l=step*relu(cv); lamFout=l; lamHout=bf16(l)
//      2 iter:   nv=relu(lamFin - step*(v - bf2f(cH))); lamFout; lamHout
//      3 iter*act
//      4 act:    actOut = (cF - v >= -TOL) ? 1 : 0  (bf16)
//      5 masked+lam1: mv=v*act; cHout=bf16(mv); l=step*relu(mv); lamFout; lamHout
//      6 final:  outF = lamFin(=u) - v
template<int EPI>
__global__ __launch_bounds__(256)
void mfma_g(const ushort_t* __restrict__ X, const ushort_t* __restrict__ W,
            const float* __restrict__ lamFin, const float* __restrict__ cF,
            const ushort_t* __restrict__ cH, const ushort_t* __restrict__ actb,
            float* __restrict__ lamFout, ushort_t* __restrict__ lamHout,
            float* __restrict__ cFout, ushort_t* __restrict__ cHout,
            ushort_t* __restrict__ actOut, float* __restrict__ outF,
            const float* __restrict__ bvec,
            int M, int N, int K) {
    __shared__ short As[2][64 * 64];     // 2 x  8 KB
    __shared__ short Bs[2][128 * 64];    // 2 x 16 KB   (48 KB total)

    const int tid = threadIdx.x;
    const int w = tid >> 6;
    const int lane = tid & 63;

    const int nbm = M >> 6;
    const int spx = nbm >> 3;
    const int xcd = blockIdx.x & 7;
    const int loc = blockIdx.x >> 3;
    const int bm = (xcd * spx + (loc % spx)) << 6;
    const int bn = (loc / spx) << 7;

    const int wm = (w & 1) * 32;
    const int wn = (w >> 1) * 64;
    const int quad = lane >> 4;
    const int l15 = lane & 15;

    const int ldr = lane >> 3;
    const int csw = ((lane & 7) ^ ldr) * 8;

    const ushort_t* Xb = X + (size_t)bm * K + csw;
    const ushort_t* Wb = W + (size_t)bn * K + csw;

    floatx4 acc[2][4] = {};

    const int KT = K >> 6;

    // prologue: stage K-tile 0 into buffer 0
#pragma unroll
    for (int t = 0; t < 2; ++t)
        GLDS(Xb + (size_t)(w * 16 + t * 8 + ldr) * K, As[0] + (w * 16 + t * 8) * 64);
#pragma unroll
    for (int t = 0; t < 4; ++t)
        GLDS(Wb + (size_t)(w * 32 + t * 8 + ldr) * K, Bs[0] + (w * 32 + t * 8) * 64);

    for (int kt = 0; kt < KT; ++kt) {
        __syncthreads();   // drains the async stage for THIS kt (vmcnt(0) at barrier)

        // prefetch kt+1 into the other buffer; stays in flight during compute,
        // drained at the next iteration's barrier.
        if (kt + 1 < KT) {
            const int nb = (kt + 1) & 1;
            const int ko = (kt + 1) << 6;
#pragma unroll
            for (int t = 0; t < 2; ++t)
                GLDS(Xb + (size_t)(w * 16 + t * 8 + ldr) * K + ko, As[nb] + (w * 16 + t * 8) * 64);
#pragma unroll
            for (int t = 0; t < 4; ++t)
                GLDS(Wb + (size_t)(w * 32 + t * 8 + ldr) * K + ko, Bs[nb] + (w * 32 + t * 8) * 64);
        }

        const int cb = kt & 1;
#pragma unroll
        for (int kk = 0; kk < 2; ++kk) {
            const int sw = ((kk * 4 + quad) ^ (l15 & 7)) * 8;
            short8 af[2], bfr[4];
#pragma unroll
            for (int i = 0; i < 2; ++i)
                af[i] = *(const short8*)(As[cb] + (wm + i * 16 + l15) * 64 + sw);
#pragma unroll
            for (int i = 0; i < 4; ++i)
                bfr[i] = *(const short8*)(Bs[cb] + (wn + i * 16 + l15) * 64 + sw);
#pragma unroll
            for (int mt = 0; mt < 2; ++mt)
#pragma unroll
                for (int nt = 0; nt < 4; ++nt)
                    acc[mt][nt] = __builtin_amdgcn_mfma_f32_16x16x32_bf16(
                        af[mt], bfr[nt], acc[mt][nt], 0, 0, 0);
        }
    }

#pragma unroll
    for (int mt = 0; mt < 2; ++mt) {
#pragma unroll
        for (int nt = 0; nt < 4; ++nt) {
#pragma unroll
            for (int r = 0; r < 4; ++r) {
                int row = bm + wm + mt * 16 + quad * 4 + r;
                int col = bn + wn + nt * 16 + l15;
                size_t idx = (size_t)row * N + col;
                float v = acc[mt][nt][r];
                if (EPI == 0) {
                    lamHout[idx] = f2bf(v);
                } else if (EPI == 1) {
                    float cv = v - bvec[col];
                    cFout[idx] = cv;
                    cHout[idx] = f2bf(cv);
                    float l = STEPV * fmaxf(cv, 0.0f);
                    lamFout[idx] = l;
                    lamHout[idx] = f2bf(l);
                } else if (EPI == 2) {
                    float nv = fmaxf(fmaf(-STEPV, v - bf2f(cH[idx]), lamFin[idx]), 0.0f);
                    lamFout[idx] = nv;
                    lamHout[idx] = f2bf(nv);
                } else if (EPI == 3) {
                    float nv = fmaxf(fmaf(-STEPV, v - bf2f(cH[idx]), lamFin[idx]), 0.0f)
                               * bf2f(actb[idx]);
                    lamFout[idx] = nv;
                    lamHout[idx] = f2bf(nv);
                } else if (EPI == 4) {
                    actOut[idx] = (cF[idx] - v >= -TOLV) ? (ushort_t)0x3F80 : (ushort_t)0;
                } else if (EPI == 5) {
                    float mv = v * bf2f(actb[idx]);
                    cHout[idx] = f2bf(mv);
                    float l = STEPV * fmaxf(mv, 0.0f);
                    lamFout[idx] = l;
                    lamHout[idx] = f2bf(l);
                } else if (EPI == 6) {
                    outF[idx] = lamFin[idx] - v;
                }
            }
        }
    }
}

static inline int grid1d(int M, int N) { return (M >> 6) * (N >> 7); }

extern "C" void kernel_launch(void* const* d_in, const int* in_sizes, int n_in,
                              void* d_out, int out_size, void* d_ws, size_t ws_size,
                              hipStream_t stream) {
    const float* x = (const float*)d_in[0];  // [B,n]
    const float* u = (const float*)d_in[1];  // [B,n]
    const float* A = (const float*)d_in[2];  // [m,n]
    const float* b = (const float*)d_in[3];  // [m]
    float* out = (float*)d_out;              // [B,n]

    const int B = 4096, n = 512, m = 1024;
    const size_t Bm = (size_t)B * m;
    const size_t Bn = (size_t)B * n;

    ushort_t* A_bf   = (ushort_t*)d_ws;            // [m,n]
    ushort_t* AT_bf  = A_bf + (size_t)m * n;       // [n,m]
    ushort_t* y_bf   = AT_bf + (size_t)n * m;      // [B,n]
    ushort_t* u_bf   = y_bf + Bn;                  // [B,n]
    ushort_t* Qbf    = u_bf + Bn;                  // [m,m]
    ushort_t* lamH_A = Qbf + (size_t)m * m;        // [B,m]
    ushort_t* lamH_B = lamH_A + Bm;                // [B,m]
    ushort_t* act    = lamH_B + Bm;                // [B,m] bf16 0/1
    ushort_t* cHbuf  = act + Bm;                   // [B,m] bf16 (c, then masked)
    float* cFbuf  = (float*)(cHbuf + Bm);          // [B,m] f32 (c, for act test)
    float* lamF_A = cFbuf + Bm;                    // [B,m] f32 master
    float* lamF_B = lamF_A + Bm;                   // [B,m] f32 master

    dim3 blk(256);

    addcast_kernel<<<(int)(Bn / 4 + 255) / 256, 256, 0, stream>>>(x, u, y_bf, u_bf, (int)Bn);
    cvt_bf16_kernel<<<(m * n / 4 + 255) / 256, 256, 0, stream>>>(A, A_bf, m * n);
    transpose_cast_kernel<<<dim3(n / 32, m / 32), dim3(256), 0, stream>>>(A, AT_bf, m, n);

    // Q = bf16(A @ A^T)
    mfma_g<0><<<grid1d(m, m), blk, 0, stream>>>(
        A_bf, A_bf, nullptr, nullptr, nullptr, nullptr,
        nullptr, Qbf, nullptr, nullptr, nullptr, nullptr, nullptr, m, m, n);

    // c = y@A^T - b; lam1 = step*relu(c) (fp32 + bf16)
    mfma_g<1><<<grid1d(B, m), blk, 0, stream>>>(
        y_bf, A_bf, nullptr, nullptr, nullptr, nullptr,
        lamF_A, lamH_A, cFbuf, cHbuf, nullptr, nullptr, b, B, m, n);

    // phase 1: 49 more iterations
    float* lfin = lamF_A; float* lfout = lamF_B;
    ushort_t* lhin = lamH_A; ushort_t* lhout = lamH_B;
    for (int it = 0; it < 49; ++it) {
        mfma_g<2><<<grid1d(B, m), blk, 0, stream>>>(
            lhin, Qbf, lfin, nullptr, cHbuf, nullptr,
            lfout, lhout, nullptr, nullptr, nullptr, nullptr, nullptr, B, m, m);
        float* tf = lfin; lfin = lfout; lfout = tf;
        ushort_t* th = lhin; lhin = lhout; lhout = th;
    }

    // active = (c - lam50@Q >= -TOL)
    mfma_g<4><<<grid1d(B, m), blk, 0, stream>>>(
        lhin, Qbf, nullptr, cFbuf, nullptr, nullptr,
        nullptr, nullptr, nullptr, nullptr, act, nullptr, nullptr, B, m, m);

    // masked = (u@A^T)*active -> cHbuf; lam1 = step*relu(masked)
    mfma_g<5><<<grid1d(B, m), blk, 0, stream>>>(
        u_bf, A_bf, nullptr, nullptr, nullptr, act,
        lamF_A, lamH_A, nullptr, cHbuf, nullptr, nullptr, nullptr, B, m, n);

    // phase 2: 9 more iterations
    lfin = lamF_A; lfout = lamF_B; lhin = lamH_A; lhout = lamH_B;
    for (int it = 0; it < 9; ++it) {
        mfma_g<3><<<grid1d(B, m), blk, 0, stream>>>(
            lhin, Qbf, lfin, nullptr, cHbuf, act,
            lfout, lhout, nullptr, nullptr, nullptr, nullptr, nullptr, B, m, m);
        float* tf = lfin; lfin = lfout; lfout = tf;
        ushort_t* th = lhin; lhin = lhout; lhout = th;
    }

    // out = u - lam @ A
    mfma_g<6><<<grid1d(B, n), blk, 0, stream>>>(
        lhin, AT_bf, u, nullptr, nullptr, nullptr,
        nullptr, nullptr, nullptr, nullptr, nullptr, out, nullptr, B, n, m);
}

// Round 11
// 1182.478 us; speedup vs baseline: 3.4337x; 1.1648x over previous
//
#include <hip/hip_runtime.h>

// ConvexPolytopeManifold: dual-PGD QP projection. B=4096, n=512, m=1024.
// Round 11: full fp16 pipeline (f16 MFMA, same rate as bf16, 8x lower input
// rounding). Single fp16 lam array = master AND MFMA operand -> iteration
// stream traffic 56 MB -> 24 MB; fp32 lam master + bf16 shadow deleted.
// cF fp32 kept only for the active-threshold test. Structure from r10:
// 64Mx128N tile, 4 waves, double-buffered LDS staging, XOR swizzle,
// XCD-aware 1D grid, dispatch-loop iterations.
//
// math:
//   Q = A@A^T; y = x+u; c = y@A^T - b
//   lam1 = step*relu(c); 49x lam = relu(lam - 0.01*(lam@Q - c))
//   active = (c - lam@Q >= -TOL)
//   masked = (u@A^T) * active; lam1 = step*relu(masked)
//   9x lam = relu(lam - 0.01*(lam@Q - masked)) * active
//   out = u - lam@A

#define TOLV 1e-5f
#define STEPV 0.01f

typedef __attribute__((ext_vector_type(8))) _Float16 half8;
typedef __attribute__((ext_vector_type(4))) float floatx4;
typedef unsigned short ushort_t;

#define GLDS(gptr, lptr) \
    __builtin_amdgcn_global_load_lds( \
        (const __attribute__((address_space(1))) void*)(gptr), \
        (__attribute__((address_space(3))) void*)(lptr), 16, 0, 0)

__device__ inline ushort_t f2h(float f) {
    union { _Float16 h; ushort_t u; } c; c.h = (_Float16)f;   // RNE
    return c.u;
}
__device__ inline float h2f(ushort_t u) {
    union { ushort_t u; _Float16 h; } c; c.u = u;
    return (float)c.h;
}

// y_h = fp16(x+u); u_h = fp16(u)
__global__ void addcast_kernel(const float* __restrict__ x, const float* __restrict__ u,
                               ushort_t* __restrict__ yh, ushort_t* __restrict__ uh, int n) {
    int idx = (blockIdx.x * blockDim.x + threadIdx.x) * 4;
    if (idx < n) {
        float4 xv = *(const float4*)(x + idx);
        float4 uv = *(const float4*)(u + idx);
        ushort4 yo, uo;
        yo.x = f2h(xv.x + uv.x); yo.y = f2h(xv.y + uv.y);
        yo.z = f2h(xv.z + uv.z); yo.w = f2h(xv.w + uv.w);
        uo.x = f2h(uv.x); uo.y = f2h(uv.y); uo.z = f2h(uv.z); uo.w = f2h(uv.w);
        *(ushort4*)(yh + idx) = yo;
        *(ushort4*)(uh + idx) = uo;
    }
}

__global__ void cvt_h_kernel(const float* __restrict__ src, ushort_t* __restrict__ dst, int n) {
    int idx = (blockIdx.x * blockDim.x + threadIdx.x) * 4;
    if (idx < n) {
        float4 v = *(const float4*)(src + idx);
        ushort4 o;
        o.x = f2h(v.x); o.y = f2h(v.y); o.z = f2h(v.z); o.w = f2h(v.w);
        *(ushort4*)(dst + idx) = o;
    }
}

__global__ void transpose_cast_kernel(const float* __restrict__ A, ushort_t* __restrict__ AT,
                                      int m, int n) {
    __shared__ float t[32][33];
    int bx = blockIdx.x * 32;
    int by = blockIdx.y * 32;
    int tx = threadIdx.x & 31, ty = threadIdx.x >> 5;   // 32 x 8
#pragma unroll
    for (int i = 0; i < 32; i += 8)
        t[ty + i][tx] = A[(size_t)(by + ty + i) * n + bx + tx];
    __syncthreads();
#pragma unroll
    for (int i = 0; i < 32; i += 8)
        AT[(size_t)(bx + ty + i) * m + by + tx] = f2h(t[tx][ty + i]);
}

// ---------------- fp16 MFMA GEMM, double-buffered:  C = X @ W^T ----------------
// X=[M,K] fp16, W=[N,K] fp16. 256 thr = 4 waves. Tile 64Mx128N, BK=64,
// wave tile 32x64 (2x4 of 16x16x32 f16). XOR-swizzled LDS; XCD-aware 1D grid.
// EPI: 0 Q:      lamOut = fp16(v)
//      1 c+lam1: cv=v-bvec[col]; cFout=cv; cHout=f2h(cv); lamOut=f2h(step*relu(cv))
//      2 iter:   nv=relu(h2f(lamIn) - step*(v - h2f(cH))); lamOut=f2h(nv)
//      3 iter*act
//      4 act:    actOut = (cF - v >= -TOL) ? 1 : 0  (fp16)
//      5 masked+lam1: mv=v*act; cHout=f2h(mv); lamOut=f2h(step*relu(mv))
//      6 final:  outF = uin - v
template<int EPI>
__global__ __launch_bounds__(256)
void mfma_g(const ushort_t* __restrict__ X, const ushort_t* __restrict__ W,
            const ushort_t* __restrict__ lamIn, const float* __restrict__ cF,
            const ushort_t* __restrict__ cH, const ushort_t* __restrict__ actb,
            ushort_t* __restrict__ lamOut, float* __restrict__ cFout,
            ushort_t* __restrict__ cHout, ushort_t* __restrict__ actOut,
            const float* __restrict__ uin, float* __restrict__ outF,
            const float* __restrict__ bvec,
            int M, int N, int K) {
    __shared__ short As[2][64 * 64];     // 2 x  8 KB
    __shared__ short Bs[2][128 * 64];    // 2 x 16 KB

    const int tid = threadIdx.x;
    const int w = tid >> 6;
    const int lane = tid & 63;

    const int nbm = M >> 6;
    const int spx = nbm >> 3;
    const int xcd = blockIdx.x & 7;
    const int loc = blockIdx.x >> 3;
    const int bm = (xcd * spx + (loc % spx)) << 6;
    const int bn = (loc / spx) << 7;

    const int wm = (w & 1) * 32;
    const int wn = (w >> 1) * 64;
    const int quad = lane >> 4;
    const int l15 = lane & 15;

    const int ldr = lane >> 3;
    const int csw = ((lane & 7) ^ ldr) * 8;

    const ushort_t* Xb = X + (size_t)bm * K + csw;
    const ushort_t* Wb = W + (size_t)bn * K + csw;

    floatx4 acc[2][4] = {};

    const int KT = K >> 6;

    // prologue: stage K-tile 0 into buffer 0
#pragma unroll
    for (int t = 0; t < 2; ++t)
        GLDS(Xb + (size_t)(w * 16 + t * 8 + ldr) * K, As[0] + (w * 16 + t * 8) * 64);
#pragma unroll
    for (int t = 0; t < 4; ++t)
        GLDS(Wb + (size_t)(w * 32 + t * 8 + ldr) * K, Bs[0] + (w * 32 + t * 8) * 64);

    for (int kt = 0; kt < KT; ++kt) {
        __syncthreads();   // drains async stage for kt

        if (kt + 1 < KT) {
            const int nb = (kt + 1) & 1;
            const int ko = (kt + 1) << 6;
#pragma unroll
            for (int t = 0; t < 2; ++t)
                GLDS(Xb + (size_t)(w * 16 + t * 8 + ldr) * K + ko, As[nb] + (w * 16 + t * 8) * 64);
#pragma unroll
            for (int t = 0; t < 4; ++t)
                GLDS(Wb + (size_t)(w * 32 + t * 8 + ldr) * K + ko, Bs[nb] + (w * 32 + t * 8) * 64);
        }

        const int cb = kt & 1;
#pragma unroll
        for (int kk = 0; kk < 2; ++kk) {
            const int sw = ((kk * 4 + quad) ^ (l15 & 7)) * 8;
            half8 af[2], bfr[4];
#pragma unroll
            for (int i = 0; i < 2; ++i)
                af[i] = *(const half8*)(As[cb] + (wm + i * 16 + l15) * 64 + sw);
#pragma unroll
            for (int i = 0; i < 4; ++i)
                bfr[i] = *(const half8*)(Bs[cb] + (wn + i * 16 + l15) * 64 + sw);
#pragma unroll
            for (int mt = 0; mt < 2; ++mt)
#pragma unroll
                for (int nt = 0; nt < 4; ++nt)
                    acc[mt][nt] = __builtin_amdgcn_mfma_f32_16x16x32_f16(
                        af[mt], bfr[nt], acc[mt][nt], 0, 0, 0);
        }
    }

    // C/D layout: row = quad*4 + r, col = lane&15 within each 16x16 tile
#pragma unroll
    for (int mt = 0; mt < 2; ++mt) {
#pragma unroll
        for (int nt = 0; nt < 4; ++nt) {
#pragma unroll
            for (int r = 0; r < 4; ++r) {
                int row = bm + wm + mt * 16 + quad * 4 + r;
                int col = bn + wn + nt * 16 + l15;
                size_t idx = (size_t)row * N + col;
                float v = acc[mt][nt][r];
                if (EPI == 0) {
                    lamOut[idx] = f2h(v);
                } else if (EPI == 1) {
                    float cv = v - bvec[col];
                    cFout[idx] = cv;
                    cHout[idx] = f2h(cv);
                    lamOut[idx] = f2h(STEPV * fmaxf(cv, 0.0f));
                } else if (EPI == 2) {
                    float nv = fmaxf(fmaf(-STEPV, v - h2f(cH[idx]), h2f(lamIn[idx])), 0.0f);
                    lamOut[idx] = f2h(nv);
                } else if (EPI == 3) {
                    float nv = fmaxf(fmaf(-STEPV, v - h2f(cH[idx]), h2f(lamIn[idx])), 0.0f);
                    nv *= h2f(actb[idx]);
                    lamOut[idx] = f2h(nv);
                } else if (EPI == 4) {
                    actOut[idx] = (cF[idx] - v >= -TOLV) ? (ushort_t)0x3C00 : (ushort_t)0;
                } else if (EPI == 5) {
                    float mv = v * h2f(actb[idx]);
                    cHout[idx] = f2h(mv);
                    lamOut[idx] = f2h(STEPV * fmaxf(mv, 0.0f));
                } else if (EPI == 6) {
                    outF[idx] = uin[idx] - v;
                }
            }
        }
    }
}

static inline int grid1d(int M, int N) { return (M >> 6) * (N >> 7); }

extern "C" void kernel_launch(void* const* d_in, const int* in_sizes, int n_in,
                              void* d_out, int out_size, void* d_ws, size_t ws_size,
                              hipStream_t stream) {
    const float* x = (const float*)d_in[0];  // [B,n]
    const float* u = (const float*)d_in[1];  // [B,n]
    const float* A = (const float*)d_in[2];  // [m,n]
    const float* b = (const float*)d_in[3];  // [m]
    float* out = (float*)d_out;              // [B,n]

    const int B = 4096, n = 512, m = 1024;
    const size_t Bm = (size_t)B * m;
    const size_t Bn = (size_t)B * n;

    ushort_t* A_h   = (ushort_t*)d_ws;             // [m,n]
    ushort_t* AT_h  = A_h + (size_t)m * n;         // [n,m]
    ushort_t* y_h   = AT_h + (size_t)n * m;        // [B,n]
    ushort_t* u_h   = y_h + Bn;                    // [B,n]
    ushort_t* Q_h   = u_h + Bn;                    // [m,m]
    ushort_t* lamA  = Q_h + (size_t)m * m;         // [B,m] fp16
    ushort_t* lamB  = lamA + Bm;                   // [B,m] fp16
    ushort_t* act   = lamB + Bm;                   // [B,m] fp16 0/1
    ushort_t* cHbuf = act + Bm;                    // [B,m] fp16 (c, then masked)
    float* cFbuf = (float*)(cHbuf + Bm);           // [B,m] f32 (c, for act test)

    dim3 blk(256);

    addcast_kernel<<<(int)(Bn / 4 + 255) / 256, 256, 0, stream>>>(x, u, y_h, u_h, (int)Bn);
    cvt_h_kernel<<<(m * n / 4 + 255) / 256, 256, 0, stream>>>(A, A_h, m * n);
    transpose_cast_kernel<<<dim3(n / 32, m / 32), dim3(256), 0, stream>>>(A, AT_h, m, n);

    // Q = fp16(A @ A^T)
    mfma_g<0><<<grid1d(m, m), blk, 0, stream>>>(
        A_h, A_h, nullptr, nullptr, nullptr, nullptr,
        Q_h, nullptr, nullptr, nullptr, nullptr, nullptr, nullptr, m, m, n);

    // c = y@A^T - b (cF fp32 + cH fp16); lamA = fp16(lam1 = step*relu(c))
    mfma_g<1><<<grid1d(B, m), blk, 0, stream>>>(
        y_h, A_h, nullptr, nullptr, nullptr, nullptr,
        lamA, cFbuf, cHbuf, nullptr, nullptr, nullptr, b, B, m, n);

    // phase 1: 49 more iterations (lam fp16 ping-pong)
    ushort_t* lin = lamA; ushort_t* lout = lamB;
    for (int it = 0; it < 49; ++it) {
        mfma_g<2><<<grid1d(B, m), blk, 0, stream>>>(
            lin, Q_h, lin, nullptr, cHbuf, nullptr,
            lout, nullptr, nullptr, nullptr, nullptr, nullptr, nullptr, B, m, m);
        ushort_t* t = lin; lin = lout; lout = t;
    }

    // active = (c - lam50@Q >= -TOL)
    mfma_g<4><<<grid1d(B, m), blk, 0, stream>>>(
        lin, Q_h, nullptr, cFbuf, nullptr, nullptr,
        nullptr, nullptr, nullptr, act, nullptr, nullptr, nullptr, B, m, m);

    // masked = (u@A^T)*active -> cHbuf; lamA = fp16(lam1 = step*relu(masked))
    mfma_g<5><<<grid1d(B, m), blk, 0, stream>>>(
        u_h, A_h, nullptr, nullptr, nullptr, act,
        lamA, nullptr, cHbuf, nullptr, nullptr, nullptr, nullptr, B, m, n);

    // phase 2: 9 more iterations
    lin = lamA; lout = lamB;
    for (int it = 0; it < 9; ++it) {
        mfma_g<3><<<grid1d(B, m), blk, 0, stream>>>(
            lin, Q_h, lin, nullptr, cHbuf, act,
            lout, nullptr, nullptr, nullptr, nullptr, nullptr, nullptr, B, m, m);
        ushort_t* t = lin; lin = lout; lout = t;
    }

    // out = u - lam @ A
    mfma_g<6><<<grid1d(B, n), blk, 0, stream>>>(
        lin, AT_h, nullptr, nullptr, nullptr, nullptr,
        nullptr, nullptr, nullptr, nullptr, u, out, nullptr, B, n, m);
}